// Round 3
// baseline (1384.675 us; speedup 1.0000x reference)
//
#include <hip/hip_runtime.h>

#define DD 40
#define BS 128        // nodes per bucket (dst >> 7)
#define MAXNB 1024    // max buckets supported by hist/scan (NB = 782 here)

__global__ void k_init(float* __restrict__ deg, int* __restrict__ counts, int n, int NB) {
  int i = blockIdx.x * blockDim.x + threadIdx.x;
  if (i < n) deg[i] = 1.0f;  // self-loop contributes 1
  if (i < NB) counts[i] = 0;
}

__global__ void k_count_deg(const int* __restrict__ dst, float* __restrict__ deg, int E) {
  int i = blockIdx.x * blockDim.x + threadIdx.x;
  if (i < E) atomicAdd(&deg[dst[i]], 1.0f);
}

__global__ void k_rsqrt_inplace(float* __restrict__ deg, int n) {
  int i = blockIdx.x * blockDim.x + threadIdx.x;
  if (i < n) deg[i] = rsqrtf(deg[i]);
}

// Per-block LDS histogram of dst-buckets, merged with one global atomic per bucket.
__global__ void k_hist(const int* __restrict__ dst, int* __restrict__ counts, int E, int NB) {
  __shared__ int lc[MAXNB];
  for (int t = threadIdx.x; t < NB; t += blockDim.x) lc[t] = 0;
  __syncthreads();
  int i = blockIdx.x * blockDim.x + threadIdx.x;
  int stride = blockDim.x * gridDim.x;
  for (; i < E; i += stride) atomicAdd(&lc[dst[i] >> 7], 1);
  __syncthreads();
  for (int t = threadIdx.x; t < NB; t += blockDim.x)
    if (lc[t]) atomicAdd(&counts[t], lc[t]);
}

// Single-block Hillis-Steele scan (NB <= 1024): exclusive starts + running cursors.
__global__ void k_scan(const int* __restrict__ counts, int* __restrict__ start,
                       int* __restrict__ cursor, int NB) {
  __shared__ int buf[2][1024];
  int t = threadIdx.x;
  int v = (t < NB) ? counts[t] : 0;
  buf[0][t] = v;
  __syncthreads();
  int pi = 0;
  for (int off = 1; off < 1024; off <<= 1) {
    int x = buf[pi][t];
    if (t >= off) x += buf[pi][t - off];
    buf[pi ^ 1][t] = x;
    __syncthreads();
    pi ^= 1;
  }
  if (t < NB) {
    int excl = buf[pi][t] - v;
    start[t] = excl;
    cursor[t] = excl;
  }
}

// Counting-sort pass: place each edge into its dst-bucket region.
// epack = (src << 7) | (dst & 127); ew = dinv[src]*dinv[dst] (reused by BOTH layers).
__global__ void k_scatter_edges(const int* __restrict__ src, const int* __restrict__ dst,
                                const float* __restrict__ dinv, int* __restrict__ cursor,
                                unsigned* __restrict__ epack, float* __restrict__ ew, int E) {
  int i = blockIdx.x * blockDim.x + threadIdx.x;
  int stride = blockDim.x * gridDim.x;
  for (; i < E; i += stride) {
    int s = src[i];
    int t = dst[i];
    int b = t >> 7;
    int pos = atomicAdd(&cursor[b], 1);
    epack[pos] = ((unsigned)s << 7) | (unsigned)(t & (BS - 1));
    ew[pos] = dinv[s] * dinv[t];
  }
}

// One block per bucket: LDS-accumulate Ahat@in for 128 nodes, then fused linear(+ReLU).
// No global atomics anywhere.
template <int RELU>
__global__ __launch_bounds__(512) void k_fused_layer(
    const float4* __restrict__ in4,      // [n*10]
    const unsigned* __restrict__ epack,  // [E] sorted by bucket
    const float* __restrict__ ew,        // [E]
    const int* __restrict__ bstart, const int* __restrict__ bcount,
    const float* __restrict__ dinv, const float* __restrict__ W,
    const float* __restrict__ bias, float* __restrict__ out, int n) {
  __shared__ float acc[BS * DD];   // 20480 B
  __shared__ float sWT[DD * DD];   // W transposed: sWT[k*40+j] = W[j*40+k]
  __shared__ float sb[DD];
  const int b = blockIdx.x;
  const int base = b * BS;
  const int nloc = min(BS, n - base);
  const int tid = threadIdx.x;

  for (int t = tid; t < DD * DD; t += 512) sWT[(t % DD) * DD + t / DD] = W[t];
  if (tid < DD) sb[tid] = bias[tid];

  // Self-loop init: acc[v] = dinv[v]^2 * in[v]
  float4* acc4 = (float4*)acc;
  for (int i = tid; i < nloc * 10; i += 512) {
    int l = i / 10;
    int q = i - l * 10;
    float w = dinv[base + l];
    w *= w;
    float4 vv = in4[(base + l) * 10 + q];
    vv.x *= w; vv.y *= w; vv.z *= w; vv.w *= w;
    acc4[i] = vv;
  }
  __syncthreads();

  // Edge accumulate: 51 edges/iter, 10 threads per edge (one float4 each), LDS atomics.
  const int e0 = bstart[b];
  const int e1 = e0 + bcount[b];
  for (int ce = e0; ce < e1; ce += 51) {
    if (tid < 510) {
      int eo = tid / 10;
      int q = tid - eo * 10;
      int e = ce + eo;
      if (e < e1) {
        unsigned pk = epack[e];
        int s = (int)(pk >> 7);
        int tl = (int)(pk & (BS - 1));
        float w = ew[e];
        float4 v = in4[s * 10 + q];
        float* a = &acc[tl * DD + q * 4];
        atomicAdd(a + 0, w * v.x);
        atomicAdd(a + 1, w * v.y);
        atomicAdd(a + 2, w * v.z);
        atomicAdd(a + 3, w * v.w);
      }
    }
  }
  __syncthreads();

  // Fused linear: out[v][j] = (relu)(bias[j] + sum_k acc[v][k] * W[j][k])
  for (int i = tid; i < nloc * DD; i += 512) {
    int l = i / DD;
    int j = i - l * DD;
    const float* row = &acc[l * DD];
    float a = sb[j];
#pragma unroll
    for (int k = 0; k < DD; ++k) a = fmaf(row[k], sWT[k * DD + j], a);
    if (RELU) a = fmaxf(a, 0.0f);
    out[(base + l) * DD + j] = a;
  }
}

extern "C" void kernel_launch(void* const* d_in, const int* in_sizes, int n_in,
                              void* d_out, int out_size, void* d_ws, size_t ws_size,
                              hipStream_t stream) {
  const float* x = (const float*)d_in[0];
  const int* ei = (const int*)d_in[1];
  const float* W1 = (const float*)d_in[2];
  const float* b1 = (const float*)d_in[3];
  const float* W2 = (const float*)d_in[4];
  const float* b2 = (const float*)d_in[5];

  const int n = in_sizes[0] / DD;  // 100000
  const int E = in_sizes[1] / 2;   // 1600000
  const int* src = ei;
  const int* dst = ei + E;
  const int NB = (n + BS - 1) / BS;  // 782

  float* out = (float*)d_out;

  // ws layout: dinv[n] | h[n*40] | ew[E] | epack[E] | counts[NB] | start[NB] | cursor[NB]
  char* w = (char*)d_ws;
  float* dinv = (float*)w;              w += (size_t)n * 4;          // 400000 (16B-mult)
  float* h = (float*)w;                 w += (size_t)n * DD * 4;     // 16 MB
  float* ew = (float*)w;                w += (size_t)E * 4;          // 6.4 MB
  unsigned* epack = (unsigned*)w;       w += (size_t)E * 4;          // 6.4 MB
  int* counts = (int*)w;                w += (size_t)MAXNB * 4;
  int* bstart = (int*)w;                w += (size_t)MAXNB * 4;
  int* cursor = (int*)w;                w += (size_t)MAXNB * 4;

  k_init<<<(n + 255) / 256, 256, 0, stream>>>(dinv, counts, n, NB);
  k_count_deg<<<(E + 255) / 256, 256, 0, stream>>>(dst, dinv, E);
  k_rsqrt_inplace<<<(n + 255) / 256, 256, 0, stream>>>(dinv, n);

  k_hist<<<1024, 256, 0, stream>>>(dst, counts, E, NB);
  k_scan<<<1, 1024, 0, stream>>>(counts, bstart, cursor, NB);
  k_scatter_edges<<<2048, 256, 0, stream>>>(src, dst, dinv, cursor, epack, ew, E);

  k_fused_layer<1><<<NB, 512, 0, stream>>>((const float4*)x, epack, ew, bstart, counts,
                                           dinv, W1, b1, h, n);
  k_fused_layer<0><<<NB, 512, 0, stream>>>((const float4*)h, epack, ew, bstart, counts,
                                           dinv, W2, b2, out, n);
}

// Round 4
// 444.506 us; speedup vs baseline: 3.1151x; 3.1151x over previous
//
#include <hip/hip_runtime.h>

#define DD 40
#define SCAN_B 1024

__global__ void k_zero32(int* __restrict__ p, int n) {
  int i = blockIdx.x * blockDim.x + threadIdx.x;
  if (i < n) p[i] = 0;
}

__global__ void k_count(const int* __restrict__ dst, int* __restrict__ ideg, int E) {
  int i = blockIdx.x * blockDim.x + threadIdx.x;
  if (i < E) atomicAdd(&ideg[dst[i]], 1);
}

__global__ void k_dinv(const int* __restrict__ ideg, float* __restrict__ dinv, int n) {
  int i = blockIdx.x * blockDim.x + threadIdx.x;
  if (i < n) dinv[i] = rsqrtf((float)(ideg[i] + 1));  // +1 = self loop
}

// xs[i] = dinv[node]*x[i], float4-vectorized (written into d_out for layer 1)
__global__ void k_prescale(const float4* __restrict__ x4, const float* __restrict__ dinv,
                           float4* __restrict__ xs4, int n4) {
  int i = blockIdx.x * blockDim.x + threadIdx.x;
  if (i < n4) {
    float w = dinv[i / 10];
    float4 v = x4[i];
    v.x *= w; v.y *= w; v.z *= w; v.w *= w;
    xs4[i] = v;
  }
}

// Block-level exclusive scan of ideg -> cursor; per-block totals -> bsum.
__global__ void k_scan1(const int* __restrict__ ideg, int* __restrict__ cursor,
                        int* __restrict__ bsum, int n) {
  __shared__ int buf[2][SCAN_B];
  int t = threadIdx.x;
  int gid = blockIdx.x * SCAN_B + t;
  int v = (gid < n) ? ideg[gid] : 0;
  buf[0][t] = v;
  __syncthreads();
  int pi = 0;
  for (int off = 1; off < SCAN_B; off <<= 1) {
    int x = buf[pi][t];
    if (t >= off) x += buf[pi][t - off];
    buf[pi ^ 1][t] = x;
    __syncthreads();
    pi ^= 1;
  }
  if (gid < n) cursor[gid] = buf[pi][t] - v;  // exclusive
  if (t == SCAN_B - 1) bsum[blockIdx.x] = buf[pi][t];
}

// Exclusive scan of bsum in place (nb <= 1024).
__global__ void k_scan2(int* __restrict__ bsum, int nb) {
  __shared__ int buf[2][SCAN_B];
  int t = threadIdx.x;
  int v = (t < nb) ? bsum[t] : 0;
  buf[0][t] = v;
  __syncthreads();
  int pi = 0;
  for (int off = 1; off < SCAN_B; off <<= 1) {
    int x = buf[pi][t];
    if (t >= off) x += buf[pi][t - off];
    buf[pi ^ 1][t] = x;
    __syncthreads();
    pi ^= 1;
  }
  if (t < nb) bsum[t] = buf[pi][t] - v;
}

__global__ void k_scan3(int* __restrict__ cursor, const int* __restrict__ bsum, int n) {
  int gid = blockIdx.x * blockDim.x + threadIdx.x;
  if (gid < n) cursor[gid] += bsum[gid >> 10];
}

// Counting sort by dst: es[bucket(t)...] = src. cursor[v] ends at rowend[v].
__global__ void k_sort(const int* __restrict__ src, const int* __restrict__ dst,
                       int* __restrict__ cursor, int* __restrict__ es, int E) {
  int i = blockIdx.x * blockDim.x + threadIdx.x;
  if (i < E) {
    int pos = atomicAdd(&cursor[dst[i]], 1);
    es[pos] = src[i];
  }
}

// Wave-per-node gather (register accumulation, no atomics) + fused linear epilogue.
// in is PRE-SCALED (xs or hs). agg[v] = dinv[v]*(in[v] + sum_e in[es[e]]).
// out element = RELU?(bias + dinv[v]*dot) ; PRESCALE multiplies by dinv[v] again for next layer.
template <int RELU, int PRESCALE>
__global__ __launch_bounds__(256) void k_layer(
    const float* __restrict__ in, const int* __restrict__ es,
    const int* __restrict__ ideg, const int* __restrict__ cursor,
    const float* __restrict__ dinv, const float* __restrict__ W,
    const float* __restrict__ bias, float* __restrict__ out, int n) {
  __shared__ float sWT[DD * DD];  // sWT[k*40+j] = W[j*40+k]
  __shared__ float sb[DD];
  __shared__ float srow[4][DD];
  const int tid = threadIdx.x;
  for (int t = tid; t < DD * DD; t += 256) sWT[(t % DD) * DD + t / DD] = W[t];
  if (tid < DD) sb[tid] = bias[tid];

  const int wid = tid >> 6, lane = tid & 63;
  const int v = blockIdx.x * 4 + wid;
  if (v < n && lane < DD) {
    const int e1 = cursor[v];          // end of bucket v (post-sort cursor)
    int e = e1 - ideg[v];              // start
    float acc0 = in[v * DD + lane];    // self-loop term (pre-scaled)
    float acc1 = 0.f;
    for (; e + 1 < e1; e += 2) {
      int s0 = es[e];
      int s1 = es[e + 1];
      acc0 += in[s0 * DD + lane];
      acc1 += in[s1 * DD + lane];
    }
    if (e < e1) acc0 += in[es[e] * DD + lane];
    srow[wid][lane] = acc0 + acc1;
  }
  __syncthreads();

  if (tid < 4 * DD) {
    int l = tid / DD, j = tid - l * DD;
    int vv = blockIdx.x * 4 + l;
    if (vv < n) {
      float dv = dinv[vv];
      const float* row = srow[l];
      float a = 0.f;
#pragma unroll
      for (int k = 0; k < DD; ++k) a = fmaf(row[k], sWT[k * DD + j], a);
      a = fmaf(a, dv, sb[j]);  // dinv[v]*dot + bias
      if (RELU) a = fmaxf(a, 0.f);
      if (PRESCALE) a *= dv;   // pre-scale for next layer's gather
      out[vv * DD + j] = a;
    }
  }
}

extern "C" void kernel_launch(void* const* d_in, const int* in_sizes, int n_in,
                              void* d_out, int out_size, void* d_ws, size_t ws_size,
                              hipStream_t stream) {
  const float* x = (const float*)d_in[0];
  const int* ei = (const int*)d_in[1];
  const float* W1 = (const float*)d_in[2];
  const float* b1 = (const float*)d_in[3];
  const float* W2 = (const float*)d_in[4];
  const float* b2 = (const float*)d_in[5];

  const int n = in_sizes[0] / DD;  // 100000
  const int E = in_sizes[1] / 2;   // 1600000
  const int* src = ei;
  const int* dst = ei + E;
  const int nD = n * DD;
  const int n4 = n * (DD / 4);
  const int nsb = (n + SCAN_B - 1) / SCAN_B;  // 98 scan blocks

  float* out = (float*)d_out;

  // ws layout (~22.5 MiB): dinv | ideg | cursor | bsum | es | hs
  char* w = (char*)d_ws;
  float* dinv = (float*)w;   w += (size_t)n * 4;
  int* ideg = (int*)w;       w += (size_t)n * 4;
  int* cursor = (int*)w;     w += (size_t)n * 4;
  int* bsum = (int*)w;       w += (size_t)SCAN_B * 4;
  int* es = (int*)w;         w += (size_t)E * 4;
  float* hs = (float*)w;     w += (size_t)nD * 4;

  // Degree + dinv
  k_zero32<<<(n + 255) / 256, 256, 0, stream>>>(ideg, n);
  k_count<<<(E + 255) / 256, 256, 0, stream>>>(dst, ideg, E);
  k_dinv<<<(n + 255) / 256, 256, 0, stream>>>(ideg, dinv, n);

  // xs = dinv*x into d_out (layer-1 gather source)
  k_prescale<<<(n4 + 255) / 256, 256, 0, stream>>>((const float4*)x, dinv, (float4*)out, n4);

  // CSR by dst: scan + counting sort (built once, used by both layers)
  k_scan1<<<nsb, SCAN_B, 0, stream>>>(ideg, cursor, bsum, n);
  k_scan2<<<1, SCAN_B, 0, stream>>>(bsum, nsb);
  k_scan3<<<(n + 255) / 256, 256, 0, stream>>>(cursor, bsum, n);
  k_sort<<<(E + 255) / 256, 256, 0, stream>>>(src, dst, cursor, es, E);

  // Layer 1: gather xs (d_out) -> hs = dinv * relu(linear)
  k_layer<1, 1><<<(n + 3) / 4, 256, 0, stream>>>(out, es, ideg, cursor, dinv, W1, b1, hs, n);
  // Layer 2: gather hs -> final out (d_out)
  k_layer<0, 0><<<(n + 3) / 4, 256, 0, stream>>>(hs, es, ideg, cursor, dinv, W2, b2, out, n);
}

// Round 5
// 299.026 us; speedup vs baseline: 4.6306x; 1.4865x over previous
//
#include <hip/hip_runtime.h>

#define DD 40
#define SCAN_B 1024
#define PITER 32  // edges per thread in XCD-partitioned kernels (chunk = 256*PITER)

__global__ void k_zero32(int* __restrict__ p, int n) {
  int i = blockIdx.x * blockDim.x + threadIdx.x;
  if (i < n) p[i] = 0;
}

// XCD-partitioned degree count: block handles chunk (blockIdx>>3), partition (blockIdx&7).
// Only edges with dst in this partition's node range are counted -> atomics stay in the
// local XCD's L2 (blockIdx%8 is round-robin across XCDs).
__global__ void k_count_p(const int* __restrict__ dst, int* __restrict__ ideg,
                          int E, int PS, int n) {
  const int p = blockIdx.x & 7;
  const int lo = p * PS;
  const int hi = min(lo + PS, n);
  const int base = (blockIdx.x >> 3) * (256 * PITER);
  for (int it = 0; it < PITER; ++it) {
    int i = base + it * 256 + threadIdx.x;
    if (i < E) {
      int t = dst[i];
      if (t >= lo && t < hi) atomicAdd(&ideg[t], 1);
    }
  }
}

// dinv[i] = rsqrt(deg+1); xs = dinv*x (written to d_out as layer-1 gather source)
__global__ void k_prescale(const float4* __restrict__ x4, const int* __restrict__ ideg,
                           float* __restrict__ dinv, float4* __restrict__ xs4, int n4, int n) {
  int i = blockIdx.x * blockDim.x + threadIdx.x;
  if (i < n) dinv[i] = rsqrtf((float)(ideg[i] + 1));
  if (i < n4) {
    float w = rsqrtf((float)(ideg[i / 10] + 1));
    float4 v = x4[i];
    v.x *= w; v.y *= w; v.z *= w; v.w *= w;
    xs4[i] = v;
  }
}

__global__ void k_scan1(const int* __restrict__ ideg, int* __restrict__ cursor,
                        int* __restrict__ bsum, int n) {
  __shared__ int buf[2][SCAN_B];
  int t = threadIdx.x;
  int gid = blockIdx.x * SCAN_B + t;
  int v = (gid < n) ? ideg[gid] : 0;
  buf[0][t] = v;
  __syncthreads();
  int pi = 0;
  for (int off = 1; off < SCAN_B; off <<= 1) {
    int x = buf[pi][t];
    if (t >= off) x += buf[pi][t - off];
    buf[pi ^ 1][t] = x;
    __syncthreads();
    pi ^= 1;
  }
  if (gid < n) cursor[gid] = buf[pi][t] - v;
  if (t == SCAN_B - 1) bsum[blockIdx.x] = buf[pi][t];
}

__global__ void k_scan2(int* __restrict__ bsum, int nb) {
  __shared__ int buf[2][SCAN_B];
  int t = threadIdx.x;
  int v = (t < nb) ? bsum[t] : 0;
  buf[0][t] = v;
  __syncthreads();
  int pi = 0;
  for (int off = 1; off < SCAN_B; off <<= 1) {
    int x = buf[pi][t];
    if (t >= off) x += buf[pi][t - off];
    buf[pi ^ 1][t] = x;
    __syncthreads();
    pi ^= 1;
  }
  if (t < nb) bsum[t] = buf[pi][t] - v;
}

__global__ void k_scan3(int* __restrict__ cursor, const int* __restrict__ bsum, int n) {
  int gid = blockIdx.x * blockDim.x + threadIdx.x;
  if (gid < n) cursor[gid] += bsum[gid >> 10];
}

// XCD-partitioned counting sort: all writes for partition p's es region + cursor range
// come from blocks (presumably) on XCD p -> L2-local RMW, single writeback.
__global__ void k_sort_p(const int* __restrict__ src, const int* __restrict__ dst,
                         int* __restrict__ cursor, int* __restrict__ es,
                         int E, int PS, int n) {
  const int p = blockIdx.x & 7;
  const int lo = p * PS;
  const int hi = min(lo + PS, n);
  const int base = (blockIdx.x >> 3) * (256 * PITER);
  for (int it = 0; it < PITER; ++it) {
    int i = base + it * 256 + threadIdx.x;
    if (i < E) {
      int t = dst[i];
      if (t >= lo && t < hi) {
        int pos = atomicAdd(&cursor[t], 1);
        es[pos] = src[i];
      }
    }
  }
}

// Gather + fused linear. 3 nodes per wave, 20 lanes x float2 per node, 4-way unrolled
// edge loop -> 12 independent 160B gathers in flight per wave. No atomics.
// in is PRE-SCALED by dinv. out = (relu)(bias + dinv[v]*dot(sumrow, W_j)) [*dinv if PRESCALE].
template <int RELU, int PRESCALE>
__global__ __launch_bounds__(256) void k_layer(
    const float2* __restrict__ in2, const int* __restrict__ es,
    const int* __restrict__ ideg, const int* __restrict__ cursor,
    const float* __restrict__ dinv, const float* __restrict__ W,
    const float* __restrict__ bias, float* __restrict__ out, int n) {
  __shared__ float sWT[DD * DD];  // sWT[k*40+j] = W[j*40+k]
  __shared__ float sb[DD];
  __shared__ float srow[12][DD];
  const int tid = threadIdx.x;
  for (int t = tid; t < DD * DD; t += 256) sWT[(t % DD) * DD + t / DD] = W[t];
  if (tid < DD) sb[tid] = bias[tid];

  const int w = tid >> 6, lane = tid & 63;
  const int g = lane / 20, pos = lane - g * 20;  // g==3 (lanes 60-63) idle
  const int v = blockIdx.x * 12 + w * 3 + g;
  if (g < 3 && v < n) {
    const int e1 = cursor[v];   // end of bucket v (cursor advanced by sort)
    int e = e1 - ideg[v];       // start
    float2 a0 = in2[v * 20 + pos];  // self-loop term (pre-scaled)
    float2 a1 = make_float2(0.f, 0.f);
    float2 a2 = make_float2(0.f, 0.f);
    float2 a3 = make_float2(0.f, 0.f);
    for (; e + 3 < e1; e += 4) {
      int s0 = es[e], s1 = es[e + 1], s2 = es[e + 2], s3 = es[e + 3];
      float2 v0 = in2[s0 * 20 + pos];
      float2 v1 = in2[s1 * 20 + pos];
      float2 v2 = in2[s2 * 20 + pos];
      float2 v3 = in2[s3 * 20 + pos];
      a0.x += v0.x; a0.y += v0.y;
      a1.x += v1.x; a1.y += v1.y;
      a2.x += v2.x; a2.y += v2.y;
      a3.x += v3.x; a3.y += v3.y;
    }
    for (; e < e1; ++e) {
      float2 vv = in2[es[e] * 20 + pos];
      a0.x += vv.x; a0.y += vv.y;
    }
    a0.x += a1.x + a2.x + a3.x;
    a0.y += a1.y + a2.y + a3.y;
    srow[w * 3 + g][2 * pos] = a0.x;
    srow[w * 3 + g][2 * pos + 1] = a0.y;
  }
  __syncthreads();

  for (int i = tid; i < 12 * DD; i += 256) {
    int l = i / DD, j = i - l * DD;
    int vv = blockIdx.x * 12 + l;
    if (vv < n) {
      float dv = dinv[vv];
      const float* row = srow[l];
      float a = 0.f;
#pragma unroll
      for (int k = 0; k < DD; ++k) a = fmaf(row[k], sWT[k * DD + j], a);
      a = fmaf(a, dv, sb[j]);
      if (RELU) a = fmaxf(a, 0.f);
      if (PRESCALE) a *= dv;
      out[vv * DD + j] = a;
    }
  }
}

extern "C" void kernel_launch(void* const* d_in, const int* in_sizes, int n_in,
                              void* d_out, int out_size, void* d_ws, size_t ws_size,
                              hipStream_t stream) {
  const float* x = (const float*)d_in[0];
  const int* ei = (const int*)d_in[1];
  const float* W1 = (const float*)d_in[2];
  const float* b1 = (const float*)d_in[3];
  const float* W2 = (const float*)d_in[4];
  const float* b2 = (const float*)d_in[5];

  const int n = in_sizes[0] / DD;  // 100000
  const int E = in_sizes[1] / 2;   // 1600000
  const int* src = ei;
  const int* dst = ei + E;
  const int nD = n * DD;
  const int n4 = n * (DD / 4);
  const int nsb = (n + SCAN_B - 1) / SCAN_B;
  const int PS = (n + 7) / 8;                        // partition size (12500)
  const int NCH = (E + 256 * PITER - 1) / (256 * PITER);  // edge chunks (196)

  float* out = (float*)d_out;

  char* w = (char*)d_ws;
  float* dinv = (float*)w;   w += (size_t)n * 4;
  int* ideg = (int*)w;       w += (size_t)n * 4;
  int* cursor = (int*)w;     w += (size_t)n * 4;
  int* bsum = (int*)w;       w += (size_t)SCAN_B * 4;
  int* es = (int*)w;         w += (size_t)E * 4;
  float* hs = (float*)w;     w += (size_t)nD * 4;

  k_zero32<<<(n + 255) / 256, 256, 0, stream>>>(ideg, n);
  k_count_p<<<NCH * 8, 256, 0, stream>>>(dst, ideg, E, PS, n);
  k_prescale<<<(n4 + 255) / 256, 256, 0, stream>>>((const float4*)x, ideg, dinv,
                                                   (float4*)out, n4, n);

  k_scan1<<<nsb, SCAN_B, 0, stream>>>(ideg, cursor, bsum, n);
  k_scan2<<<1, SCAN_B, 0, stream>>>(bsum, nsb);
  k_scan3<<<(n + 255) / 256, 256, 0, stream>>>(cursor, bsum, n);
  k_sort_p<<<NCH * 8, 256, 0, stream>>>(src, dst, cursor, es, E, PS, n);

  k_layer<1, 1><<<(n + 11) / 12, 256, 0, stream>>>((const float2*)out, es, ideg, cursor,
                                                   dinv, W1, b1, hs, n);
  k_layer<0, 0><<<(n + 11) / 12, 256, 0, stream>>>((const float2*)hs, es, ideg, cursor,
                                                   dinv, W2, b2, out, n);
}

// Round 6
// 260.826 us; speedup vs baseline: 5.3088x; 1.1465x over previous
//
#include <hip/hip_runtime.h>
#include <hip/hip_fp16.h>

#define DD 40
#define SCAN_B 1024
#define PITER 32  // edges per thread in XCD-partitioned kernels (chunk = 256*PITER)

// XCD-partitioned degree count (blockIdx&7 -> round-robin XCD; atomics stay L2-local)
__global__ void k_count_p(const int* __restrict__ dst, int* __restrict__ ideg,
                          int E, int PS, int n) {
  const int p = blockIdx.x & 7;
  const int lo = p * PS;
  const int hi = min(lo + PS, n);
  const int base = (blockIdx.x >> 3) * (256 * PITER);
  for (int it = 0; it < PITER; ++it) {
    int i = base + it * 256 + threadIdx.x;
    if (i < E) {
      int t = dst[i];
      if (t >= lo && t < hi) atomicAdd(&ideg[t], 1);
    }
  }
}

// dinv[i] = rsqrt(deg+1); xs = fp16(dinv*x) (layer-1 gather source, 80B rows)
__global__ void k_prescale(const float4* __restrict__ x4, const int* __restrict__ ideg,
                           float* __restrict__ dinv, uint2* __restrict__ xs8,
                           int n4, int n) {
  int i = blockIdx.x * blockDim.x + threadIdx.x;
  if (i < n) dinv[i] = rsqrtf((float)(ideg[i] + 1));
  if (i < n4) {
    float w = rsqrtf((float)(ideg[i / 10] + 1));
    float4 v = x4[i];
    __half2 ha = __float22half2_rn(make_float2(v.x * w, v.y * w));
    __half2 hb = __float22half2_rn(make_float2(v.z * w, v.w * w));
    uint2 u;
    u.x = *(unsigned*)&ha;
    u.y = *(unsigned*)&hb;
    xs8[i] = u;
  }
}

__global__ void k_scan1(const int* __restrict__ ideg, int* __restrict__ cursor,
                        int* __restrict__ bsum, int n) {
  __shared__ int buf[2][SCAN_B];
  int t = threadIdx.x;
  int gid = blockIdx.x * SCAN_B + t;
  int v = (gid < n) ? ideg[gid] : 0;
  buf[0][t] = v;
  __syncthreads();
  int pi = 0;
  for (int off = 1; off < SCAN_B; off <<= 1) {
    int x = buf[pi][t];
    if (t >= off) x += buf[pi][t - off];
    buf[pi ^ 1][t] = x;
    __syncthreads();
    pi ^= 1;
  }
  if (gid < n) cursor[gid] = buf[pi][t] - v;
  if (t == SCAN_B - 1) bsum[blockIdx.x] = buf[pi][t];
}

__global__ void k_scan2(int* __restrict__ bsum, int nb) {
  __shared__ int buf[2][SCAN_B];
  int t = threadIdx.x;
  int v = (t < nb) ? bsum[t] : 0;
  buf[0][t] = v;
  __syncthreads();
  int pi = 0;
  for (int off = 1; off < SCAN_B; off <<= 1) {
    int x = buf[pi][t];
    if (t >= off) x += buf[pi][t - off];
    buf[pi ^ 1][t] = x;
    __syncthreads();
    pi ^= 1;
  }
  if (t < nb) bsum[t] = buf[pi][t] - v;
}

__global__ void k_scan3(int* __restrict__ cursor, const int* __restrict__ bsum, int n) {
  int gid = blockIdx.x * blockDim.x + threadIdx.x;
  if (gid < n) cursor[gid] += bsum[gid >> 10];
}

// XCD-partitioned counting sort: cursor atomics + es writes land in local L2.
__global__ void k_sort_p(const int* __restrict__ src, const int* __restrict__ dst,
                         int* __restrict__ cursor, int* __restrict__ es,
                         int E, int PS, int n) {
  const int p = blockIdx.x & 7;
  const int lo = p * PS;
  const int hi = min(lo + PS, n);
  const int base = (blockIdx.x >> 3) * (256 * PITER);
  for (int it = 0; it < PITER; ++it) {
    int i = base + it * 256 + threadIdx.x;
    if (i < E) {
      int t = dst[i];
      if (t >= lo && t < hi) {
        int pos = atomicAdd(&cursor[t], 1);
        es[pos] = src[i];
      }
    }
  }
}

// Gather (fp16 rows, fp32 accumulate) + fused linear epilogue. 6 nodes/wave,
// 10 lanes x uint2(4 fp16) per node, 4-way unroll -> 24 gathers in flight/wave.
// in is PRE-SCALED by dinv. OUT_HALF: relu, *dinv (next-layer prescale), half2 out.
template <int OUT_HALF>
__global__ __launch_bounds__(256) void k_layer(
    const uint2* __restrict__ in8, const int* __restrict__ es,
    const int* __restrict__ ideg, const int* __restrict__ cursor,
    const float* __restrict__ dinv, const float* __restrict__ W,
    const float* __restrict__ bias, float* __restrict__ outf,
    __half2* __restrict__ outh, int n) {
  __shared__ float sWT[DD * DD];  // sWT[k*40+j] = W[j*40+k]
  __shared__ float sb[DD];
  __shared__ float srow[24][DD];
  const int tid = threadIdx.x;
  for (int t = tid; t < DD * DD; t += 256) sWT[(t % DD) * DD + t / DD] = W[t];
  if (tid < DD) sb[tid] = bias[tid];

  const int w = tid >> 6, lane = tid & 63;
  const int g = lane / 10, pos = lane - g * 10;  // g==6 (lanes 60-63) idle
  const int v = blockIdx.x * 24 + w * 6 + g;
  if (g < 6 && v < n) {
    const int e1 = cursor[v];  // end of bucket v (cursor advanced by sort)
    int e = e1 - ideg[v];      // start
    uint2 u = in8[(size_t)v * 10 + pos];  // self-loop term
    float2 f0 = __half22float2(*(const __half2*)&u.x);
    float2 f1 = __half22float2(*(const __half2*)&u.y);
    float a0 = f0.x, a1 = f0.y, a2 = f1.x, a3 = f1.y;
    float b0 = 0, b1 = 0, b2 = 0, b3 = 0;
    float c0 = 0, c1 = 0, c2 = 0, c3 = 0;
    float d0 = 0, d1 = 0, d2 = 0, d3 = 0;
    for (; e + 3 < e1; e += 4) {
      int s0 = es[e], s1 = es[e + 1], s2 = es[e + 2], s3 = es[e + 3];
      uint2 u0 = in8[(size_t)s0 * 10 + pos];
      uint2 u1 = in8[(size_t)s1 * 10 + pos];
      uint2 u2 = in8[(size_t)s2 * 10 + pos];
      uint2 u3 = in8[(size_t)s3 * 10 + pos];
      float2 p0 = __half22float2(*(const __half2*)&u0.x);
      float2 q0 = __half22float2(*(const __half2*)&u0.y);
      a0 += p0.x; a1 += p0.y; a2 += q0.x; a3 += q0.y;
      float2 p1 = __half22float2(*(const __half2*)&u1.x);
      float2 q1 = __half22float2(*(const __half2*)&u1.y);
      b0 += p1.x; b1 += p1.y; b2 += q1.x; b3 += q1.y;
      float2 p2 = __half22float2(*(const __half2*)&u2.x);
      float2 q2 = __half22float2(*(const __half2*)&u2.y);
      c0 += p2.x; c1 += p2.y; c2 += q2.x; c3 += q2.y;
      float2 p3 = __half22float2(*(const __half2*)&u3.x);
      float2 q3 = __half22float2(*(const __half2*)&u3.y);
      d0 += p3.x; d1 += p3.y; d2 += q3.x; d3 += q3.y;
    }
    for (; e < e1; ++e) {
      uint2 uu = in8[(size_t)es[e] * 10 + pos];
      float2 pp = __half22float2(*(const __half2*)&uu.x);
      float2 qq = __half22float2(*(const __half2*)&uu.y);
      a0 += pp.x; a1 += pp.y; a2 += qq.x; a3 += qq.y;
    }
    float* r = &srow[w * 6 + g][4 * pos];
    r[0] = a0 + b0 + c0 + d0;
    r[1] = a1 + b1 + c1 + d1;
    r[2] = a2 + b2 + c2 + d2;
    r[3] = a3 + b3 + c3 + d3;
  }
  __syncthreads();

  if (OUT_HALF) {
    // 24 nodes x 20 half2 outputs
    for (int i = tid; i < 24 * 20; i += 256) {
      int l = i / 20, jj = i - l * 20;
      int vv = blockIdx.x * 24 + l;
      if (vv < n) {
        float dv = dinv[vv];
        const float* row = srow[l];
        float s0 = 0.f, s1 = 0.f;
#pragma unroll
        for (int k = 0; k < DD; ++k) {
          s0 = fmaf(row[k], sWT[k * DD + 2 * jj], s0);
          s1 = fmaf(row[k], sWT[k * DD + 2 * jj + 1], s1);
        }
        s0 = fmaf(s0, dv, sb[2 * jj]);
        s1 = fmaf(s1, dv, sb[2 * jj + 1]);
        s0 = fmaxf(s0, 0.f) * dv;  // relu + next-layer prescale
        s1 = fmaxf(s1, 0.f) * dv;
        outh[(size_t)vv * 20 + jj] = __float22half2_rn(make_float2(s0, s1));
      }
    }
  } else {
    for (int i = tid; i < 24 * DD; i += 256) {
      int l = i / DD, j = i - l * DD;
      int vv = blockIdx.x * 24 + l;
      if (vv < n) {
        float dv = dinv[vv];
        const float* row = srow[l];
        float a = 0.f;
#pragma unroll
        for (int k = 0; k < DD; ++k) a = fmaf(row[k], sWT[k * DD + j], a);
        outf[(size_t)vv * DD + j] = fmaf(a, dv, sb[j]);
      }
    }
  }
}

extern "C" void kernel_launch(void* const* d_in, const int* in_sizes, int n_in,
                              void* d_out, int out_size, void* d_ws, size_t ws_size,
                              hipStream_t stream) {
  const float* x = (const float*)d_in[0];
  const int* ei = (const int*)d_in[1];
  const float* W1 = (const float*)d_in[2];
  const float* b1 = (const float*)d_in[3];
  const float* W2 = (const float*)d_in[4];
  const float* b2 = (const float*)d_in[5];

  const int n = in_sizes[0] / DD;  // 100000
  const int E = in_sizes[1] / 2;   // 1600000
  const int* src = ei;
  const int* dst = ei + E;
  const int n4 = n * (DD / 4);
  const int nsb = (n + SCAN_B - 1) / SCAN_B;
  const int PS = (n + 7) / 8;
  const int NCH = (E + 256 * PITER - 1) / (256 * PITER);

  float* out = (float*)d_out;

  // ws (~24 MB): dinv | ideg | cursor | bsum | es | xs(fp16) | hs(fp16)
  char* w = (char*)d_ws;
  float* dinv = (float*)w;   w += (size_t)n * 4;
  int* ideg = (int*)w;       w += (size_t)n * 4;
  int* cursor = (int*)w;     w += (size_t)n * 4;
  int* bsum = (int*)w;       w += (size_t)SCAN_B * 4;
  int* es = (int*)w;         w += (size_t)E * 4;
  uint2* xs8 = (uint2*)w;    w += (size_t)n * DD * 2;
  uint2* hs8 = (uint2*)w;    w += (size_t)n * DD * 2;

  hipMemsetAsync(ideg, 0, (size_t)n * 4, stream);
  k_count_p<<<NCH * 8, 256, 0, stream>>>(dst, ideg, E, PS, n);
  k_prescale<<<(n4 + 255) / 256, 256, 0, stream>>>((const float4*)x, ideg, dinv, xs8, n4, n);

  k_scan1<<<nsb, SCAN_B, 0, stream>>>(ideg, cursor, bsum, n);
  k_scan2<<<1, SCAN_B, 0, stream>>>(bsum, nsb);
  k_scan3<<<(n + 255) / 256, 256, 0, stream>>>(cursor, bsum, n);
  k_sort_p<<<NCH * 8, 256, 0, stream>>>(src, dst, cursor, es, E, PS, n);

  const int NBK = (n + 23) / 24;
  // Layer 1: gather xs -> hs = fp16(dinv*relu(linear))
  k_layer<1><<<NBK, 256, 0, stream>>>(xs8, es, ideg, cursor, dinv, W1, b1,
                                      nullptr, (__half2*)hs8, n);
  // Layer 2: gather hs -> final fp32 out
  k_layer<0><<<NBK, 256, 0, stream>>>(hs8, es, ideg, cursor, dinv, W2, b2,
                                      out, nullptr, n);
}